// Round 13
// baseline (69.273 us; speedup 1.0000x reference)
//
#include <hip/hip_runtime.h>
#include <hip/hip_bf16.h>

#define NORM 0.35355339059327373f  // 64^-0.25
#define EPS 1e-6f

typedef __attribute__((ext_vector_type(8))) short short8;
typedef __attribute__((ext_vector_type(4))) float floatx4;

static __device__ __forceinline__ ushort f2bf(float x) {
  union { __hip_bfloat16 h; ushort u; } c;
  c.h = __float2bfloat16(x);
  return c.u;
}
static __device__ __forceinline__ ushort2 f2bf2(float a, float b) {
  union { __hip_bfloat162 h; ushort2 u; } c;
  c.h = __float22bfloat162_rn(make_float2(a, b));
  return c.u;
}
static __device__ __forceinline__ float sigm(float s) {
  return __builtin_amdgcn_rcpf(1.f + __expf(-s)) + EPS;
}
#define MFMA __builtin_amdgcn_mfma_f32_16x16x32_bf16

// ws layout (bytes):
//   [0, 32768)            prjg: bf16(proj*NORM) [256 feat][64 d]
//   [32768, 557056)       ksumg: f32 per-chunk Ksum [512][256] (k2 -> exclusive prefix)
//   [557056, +16777216)   stg: bf16 St [512][64 e][256 f] (k2 -> exclusive prefix)

// ---------------- K0: pre-convert proj ----------------
__global__ __launch_bounds__(256) void k0_proj(const float* __restrict__ proj,
                                               ushort* __restrict__ prjg) {
  int id = blockIdx.x * 256 + threadIdx.x;  // 4096 float4s
  float4 a = ((const float4*)proj)[id];
  ushort2 lo = f2bf2(a.x * NORM, a.y * NORM);
  ushort2 hi = f2bf2(a.z * NORM, a.w * NORM);
  ((ushort4*)prjg)[id] = make_ushort4(lo.x, lo.y, hi.x, hi.y);
}

// ---------------- K1: per-chunk sums (8 waves, f-quarters, kpt dbuf, pj prefetch) ----------------
__global__ __launch_bounds__(512, 4) void k1_chunksums(
    const float* __restrict__ k, const float* __restrict__ v,
    const ushort* __restrict__ prjg, float* __restrict__ ksumg,
    ushort* __restrict__ stg) {
  __shared__ __align__(16) ushort xk[128 * 72];       // k chunk pos-major bf16
  __shared__ __align__(16) ushort vt[80 * 136];       // V e-major + ones row e=64
  __shared__ __align__(16) ushort kpt[2 * 64 * 136];  // Kp quarter, feat-major, dbuf
  const int t = threadIdx.x;
  const int w = t >> 6, l = t & 63, lr = l & 15, lg = l >> 4;
  const int blk = blockIdx.x;
  const float4* kg4 = (const float4*)(k + (size_t)blk * 8192);
  const float4* vg4 = (const float4*)(v + (size_t)blk * 8192);

  // staging loads FIRST (needed before B0); pj fragments after (needed after B0)
  #pragma unroll
  for (int u = 0; u < 4; ++u) {
    int id = t + u * 512;
    float4 a = kg4[id];
    int row = id >> 4, c = (id & 15) * 4;
    ushort2 p0 = f2bf2(a.x, a.y), p1 = f2bf2(a.z, a.w);
    *(ushort4*)&xk[row * 72 + c] = make_ushort4(p0.x, p0.y, p1.x, p1.y);
  }
  #pragma unroll
  for (int u = 0; u < 4; ++u) {
    int id = t + u * 512;
    float4 a = vg4[id];
    int pos = id >> 4, e = (id & 15) * 4;
    vt[(e + 0) * 136 + pos] = f2bf(a.x);
    vt[(e + 1) * 136 + pos] = f2bf(a.y);
    vt[(e + 2) * 136 + pos] = f2bf(a.z);
    vt[(e + 3) * 136 + pos] = f2bf(a.w);
  }
  // quarter-0 prjg fragments (latency hides under the ones-row writes + B0)
  short8 pj[2][8];
  #pragma unroll
  for (int i = 0; i < 4; ++i) {
    pj[0][2 * i] = *(const short8*)&prjg[(size_t)(i * 16 + lr) * 64 + lg * 8];
    pj[0][2 * i + 1] = *(const short8*)&prjg[(size_t)(i * 16 + lr) * 64 + 32 + lg * 8];
  }
  #pragma unroll
  for (int u = 0; u < 4; ++u) {  // rows 64..79: ones row then zeros
    int id = t + u * 512;
    int rr = id >> 7, pos = id & 127;
    vt[(64 + rr) * 136 + pos] = (rr == 0) ? (ushort)0x3F80 : (ushort)0;
  }
  __syncthreads();

  const int fb = w & 3, g = w >> 2;
  float* kb = ksumg + (size_t)blk * 256;
  ushort* stbp = stg + (size_t)blk * 16384;

  // loop-invariant xk fragments (wave's pos-block rows)
  const short8 a0 = *(const short8*)&xk[(w * 16 + lr) * 72 + lg * 8];
  const short8 a1 = *(const short8*)&xk[(w * 16 + lr) * 72 + 32 + lg * 8];

  #pragma unroll
  for (int qd = 0; qd < 4; ++qd) {
    const int cur = qd & 1, nxt = cur ^ 1;
    ushort* kq = kpt + cur * 8704;
    // features: wave w = pos-block w; M=pos, N=feat(4 blocks), K=d(64)
    #pragma unroll
    for (int fb2 = 0; fb2 < 4; ++fb2) {
      floatx4 fa = (floatx4){0.f, 0.f, 0.f, 0.f};
      fa = MFMA(a0, pj[cur][2 * fb2], fa, 0, 0, 0);
      fa = MFMA(a1, pj[cur][2 * fb2 + 1], fa, 0, 0, 0);
      // C: col=feat(lr), row=pos(w*16+lg*4+r) -> 4 consecutive pos, b64
      ushort2 p0 = f2bf2(sigm(fa[0]), sigm(fa[1]));
      ushort2 p1 = f2bf2(sigm(fa[2]), sigm(fa[3]));
      *(ushort4*)&kq[(fb2 * 16 + lr) * 136 + w * 16 + lg * 4] =
          make_ushort4(p0.x, p0.y, p1.x, p1.y);
    }
    __syncthreads();  // kq[cur] ready (single barrier per stage; dbuf makes it safe)

    if (qd < 3) {  // prefetch next quarter's prjg fragments (hide under S-GEMM)
      #pragma unroll
      for (int i = 0; i < 4; ++i) {
        pj[nxt][2 * i] =
            *(const short8*)&prjg[(size_t)((qd + 1) * 64 + i * 16 + lr) * 64 + lg * 8];
        pj[nxt][2 * i + 1] =
            *(const short8*)&prjg[(size_t)((qd + 1) * 64 + i * 16 + lr) * 64 + 32 + lg * 8];
      }
    }

    // S-GEMM quarter: M=feat(fb), N=e'(g, 2+g, (+ones if g==0)), K=pos(128)
    {
      floatx4 s0 = (floatx4){0.f, 0.f, 0.f, 0.f};
      floatx4 s1 = (floatx4){0.f, 0.f, 0.f, 0.f};
      floatx4 s2 = (floatx4){0.f, 0.f, 0.f, 0.f};
      __builtin_amdgcn_s_setprio(1);
      #pragma unroll
      for (int ks = 0; ks < 4; ++ks) {
        short8 a = *(const short8*)&kq[(fb * 16 + lr) * 136 + ks * 32 + lg * 8];
        short8 bA = *(const short8*)&vt[(g * 16 + lr) * 136 + ks * 32 + lg * 8];
        s0 = MFMA(a, bA, s0, 0, 0, 0);
        short8 bB = *(const short8*)&vt[((2 + g) * 16 + lr) * 136 + ks * 32 + lg * 8];
        s1 = MFMA(a, bB, s1, 0, 0, 0);
        if (g == 0) {
          short8 bC = *(const short8*)&vt[(64 + lr) * 136 + ks * 32 + lg * 8];
          s2 = MFMA(a, bC, s2, 0, 0, 0);
        }
      }
      __builtin_amdgcn_s_setprio(0);
      {
        ushort2 q0 = f2bf2(s0[0], s0[1]), q1 = f2bf2(s0[2], s0[3]);
        *(ushort4*)&stbp[(size_t)(g * 16 + lr) * 256 + qd * 64 + fb * 16 + lg * 4] =
            make_ushort4(q0.x, q0.y, q1.x, q1.y);
        ushort2 r0_ = f2bf2(s1[0], s1[1]), r1_ = f2bf2(s1[2], s1[3]);
        *(ushort4*)&stbp[(size_t)((2 + g) * 16 + lr) * 256 + qd * 64 + fb * 16 + lg * 4] =
            make_ushort4(r0_.x, r0_.y, r1_.x, r1_.y);
      }
      if (g == 0 && lr == 0) {
        #pragma unroll
        for (int r = 0; r < 4; ++r) kb[qd * 64 + fb * 16 + lg * 4 + r] = s2[r];
      }
    }
    // no trailing barrier: next qd writes the other kpt buffer
  }
}

// ---------------- K2: exclusive scan over 32 chunks per head ----------------
// batch-load all 32 chunk values (independent loads in flight), then scan in regs
__global__ __launch_bounds__(256) void k2_scan(float* __restrict__ ksumg,
                                               ushort* __restrict__ stg) {
  int bh = blockIdx.x / 33, part = blockIdx.x % 33, t = threadIdx.x;
  if (part < 32) {
    uint* p = (uint*)stg + (size_t)bh * 32 * 8192 + part * 256 + t;
    uint tmp[32];
    #pragma unroll
    for (int c = 0; c < 32; ++c) tmp[c] = p[(size_t)c * 8192];
    float r0 = 0.f, r1 = 0.f;
    #pragma unroll
    for (int c = 0; c < 32; ++c) {
      float a = __uint_as_float(tmp[c] << 16);
      float b = __uint_as_float(tmp[c] & 0xffff0000u);
      ushort2 w2 = f2bf2(r0, r1);
      p[(size_t)c * 8192] = (uint)w2.x | ((uint)w2.y << 16);
      r0 += a; r1 += b;
    }
  } else {
    float* p = ksumg + (size_t)bh * 32 * 256 + t;
    float tmp[32];
    #pragma unroll
    for (int c = 0; c < 32; ++c) tmp[c] = p[(size_t)c * 256];
    float run = 0.f;
    #pragma unroll
    for (int c = 0; c < 32; ++c) {
      p[(size_t)c * 256] = run;
      run += tmp[c];
    }
  }
}

// ---------------- K3: per-chunk output (8 waves, f-quarters, 2 blk/CU, pipelined) ----------------
__global__ __launch_bounds__(512, 4) void k3_out(
    const float* __restrict__ q, const float* __restrict__ k,
    const float* __restrict__ v, const ushort* __restrict__ prjg,
    const float* __restrict__ ksumg, const ushort* __restrict__ stg,
    float* __restrict__ out) {
  __shared__ __align__(16) union U0 {
    struct { ushort xq[128 * 72]; ushort xk[128 * 72]; } s;  // 36864 B
    ushort ab[128 * 136];                                    // 34816 B (tail)
  } r0;
  __shared__ __align__(16) union U1 {
    ushort qp[128 * 72];   // Qp quarter, pos-major
    ushort vt[64 * 136];   // V^T (tail)
  } r1;
  __shared__ __align__(16) ushort kp[144 * 72];  // Kp quarter + Kprev row 128 (+zeros)
  __shared__ float den[128];
  // LDS total = 36864 + 18432 + 20736 + 512 = 76544 B -> 2 blocks/CU

  const int t = threadIdx.x;
  const int w = t >> 6, l = t & 63, lr = l & 15, lg = l >> 4;
  const int blk = blockIdx.x;
  const float4* qg4 = (const float4*)(q + (size_t)blk * 8192);
  const float4* kg4 = (const float4*)(k + (size_t)blk * 8192);
  const float4* vg4 = (const float4*)(v + (size_t)blk * 8192);
  const float* ksb = ksumg + (size_t)blk * 256;
  const ushort* stb = stg + (size_t)blk * 16384;
  float* outg = out + (size_t)blk * 8192;

  // Kprev scalars (wave-0 lanes hold them; written into kp row 128 per quarter)
  float kv0 = 0.f, kv1 = 0.f, kv2 = 0.f, kv3 = 0.f;
  if (t < 64) {
    kv0 = ksb[t]; kv1 = ksb[64 + t]; kv2 = ksb[128 + t]; kv3 = ksb[192 + t];
  }
  // zero kp rows 129..143 once (dqr B-fragment padding)
  for (int id = t; id < 1080; id += 512) kp[9288 + id] = (ushort)0;

  // stage xq/xk
  #pragma unroll
  for (int u = 0; u < 4; ++u) {
    int id = t + u * 512;
    float4 a = qg4[id];
    float4 c = kg4[id];
    int row = id >> 4, cc = (id & 15) * 4;
    ushort2 a0 = f2bf2(a.x, a.y), a1 = f2bf2(a.z, a.w);
    *(ushort4*)&r0.s.xq[row * 72 + cc] = make_ushort4(a0.x, a0.y, a1.x, a1.y);
    ushort2 c0 = f2bf2(c.x, c.y), c1 = f2bf2(c.z, c.w);
    *(ushort4*)&r0.s.xk[row * 72 + cc] = make_ushort4(c0.x, c0.y, c1.x, c1.y);
  }
  __syncthreads();  // B0

  floatx4 Aacc[9];  // A blocks 0..7 (pos-block w) + dqr column (8)
  floatx4 Oacc[4];  // O tiles (eb, qh)
  #pragma unroll
  for (int i = 0; i < 9; ++i) Aacc[i] = (floatx4){0.f, 0.f, 0.f, 0.f};
  #pragma unroll
  for (int i = 0; i < 4; ++i) Oacc[i] = (floatx4){0.f, 0.f, 0.f, 0.f};
  const int px = w & 1, fbw = w >> 1;  // feature role
  const int eb = w & 3, qh = w >> 2;   // O role
  float4 fva, fvb, fvc, fvd;

  // 2-deep fragment pipeline: pjc/stc[cur] consumed this quarter, [nxt] loaded
  // after B1 so the latency hides under A/O1.  Indices static after full unroll.
  short8 pjc[2][2], stc[2][2];
  pjc[0][0] = *(const short8*)&prjg[(size_t)(fbw * 16 + lr) * 64 + lg * 8];
  pjc[0][1] = *(const short8*)&prjg[(size_t)(fbw * 16 + lr) * 64 + 32 + lg * 8];
  stc[0][0] = *(const short8*)&stb[(size_t)(eb * 16 + lr) * 256 + lg * 8];
  stc[0][1] = *(const short8*)&stb[(size_t)(eb * 16 + lr) * 256 + 32 + lg * 8];

  #pragma unroll
  for (int qd = 0; qd < 4; ++qd) {
    const int cur = qd & 1, nxt = cur ^ 1;
    if (t < 64) {
      float kvq = qd == 0 ? kv0 : qd == 1 ? kv1 : qd == 2 ? kv2 : kv3;
      kp[9216 + t] = f2bf(kvq + EPS);  // row 128
    }
    // features: M=feat(fbw), N=pos(8 blocks in 2 halves), K=d(64)
    const ushort* xb = px ? r0.s.xk : r0.s.xq;
    ushort* xp = px ? kp : r1.qp;
    #pragma unroll
    for (int h = 0; h < 2; ++h) {
      floatx4 fa[4];
      #pragma unroll
      for (int i = 0; i < 4; ++i) fa[i] = (floatx4){0.f, 0.f, 0.f, 0.f};
      #pragma unroll
      for (int ks2 = 0; ks2 < 2; ++ks2) {
        short8 a = pjc[cur][ks2];
        #pragma unroll
        for (int nb4 = 0; nb4 < 4; ++nb4) {
          int nb = h * 4 + nb4;
          short8 b = *(const short8*)&xb[(nb * 16 + lr) * 72 + ks2 * 32 + lg * 8];
          fa[nb4] = MFMA(a, b, fa[nb4], 0, 0, 0);
        }
      }
      #pragma unroll
      for (int nb4 = 0; nb4 < 4; ++nb4) {
        int nb = h * 4 + nb4;
        // C: col=pos(lr), row=feat (4 consecutive) -> b64 into [pos][feat]
        ushort2 p0 = f2bf2(sigm(fa[nb4][0]), sigm(fa[nb4][1]));
        ushort2 p1 = f2bf2(sigm(fa[nb4][2]), sigm(fa[nb4][3]));
        *(ushort4*)&xp[(nb * 16 + lr) * 72 + fbw * 16 + lg * 4] =
            make_ushort4(p0.x, p0.y, p1.x, p1.y);
      }
    }
    __syncthreads();  // B1(qd)

    if (qd < 3) {  // prefetch next quarter's fragments (lands during A/O1)
      pjc[nxt][0] = *(const short8*)&prjg[(size_t)((qd + 1) * 64 + fbw * 16 + lr) * 64 + lg * 8];
      pjc[nxt][1] = *(const short8*)&prjg[(size_t)((qd + 1) * 64 + fbw * 16 + lr) * 64 + 32 + lg * 8];
      stc[nxt][0] = *(const short8*)&stb[(size_t)(eb * 16 + lr) * 256 + (qd + 1) * 64 + lg * 8];
      stc[nxt][1] = *(const short8*)&stb[(size_t)(eb * 16 + lr) * 256 + (qd + 1) * 64 + 32 + lg * 8];
    }
    if (qd == 2) {  // tail V loads issued a full quarter early: latency hides
      fva = vg4[t]; fvb = vg4[t + 512]; fvc = vg4[t + 1024]; fvd = vg4[t + 1536];
    }

    __builtin_amdgcn_s_setprio(1);
    // A-GEMM (causal, static unroll+predicate: rule #20) + dqr column
    #pragma unroll
    for (int ks = 0; ks < 2; ++ks) {
      short8 aq = *(const short8*)&r1.qp[(w * 16 + lr) * 72 + ks * 32 + lg * 8];
      #pragma unroll
      for (int nb = 0; nb < 8; ++nb) {
        if (nb <= w) {
          short8 bk = *(const short8*)&kp[(nb * 16 + lr) * 72 + ks * 32 + lg * 8];
          Aacc[nb] = MFMA(aq, bk, Aacc[nb], 0, 0, 0);
        }
      }
      short8 bx = *(const short8*)&kp[(128 + lr) * 72 + ks * 32 + lg * 8];
      Aacc[8] = MFMA(aq, bx, Aacc[8], 0, 0, 0);
    }
    // O1^T: O^T += S_prev^T Qp^T (A-frag from regs)
    #pragma unroll
    for (int ks = 0; ks < 2; ++ks) {
      short8 as = stc[cur][ks];
      #pragma unroll
      for (int nq = 0; nq < 4; ++nq) {
        int jb = qh * 4 + nq;
        short8 bq = *(const short8*)&r1.qp[(jb * 16 + lr) * 72 + ks * 32 + lg * 8];
        Oacc[nq] = MFMA(as, bq, Oacc[nq], 0, 0, 0);
      }
    }
    __builtin_amdgcn_s_setprio(0);
    __syncthreads();  // B2(qd)
  }

  // mask + rowsum -> den
  #pragma unroll
  for (int r = 0; r < 4; ++r) {
    const int qrow = w * 16 + lg * 4 + r;
    float s = 0.f;
    #pragma unroll
    for (int nb = 0; nb < 8; ++nb) {
      float val = Aacc[nb][r];
      if (nb * 16 + lr > qrow) val = 0.f;
      Aacc[nb][r] = val;
      s += val;
    }
    s += __shfl_xor(s, 1); s += __shfl_xor(s, 2);
    s += __shfl_xor(s, 4); s += __shfl_xor(s, 8);
    if (lr == 0) den[qrow] = s + Aacc[8][r];
  }
  // scatter masked A -> ab
  #pragma unroll
  for (int nb = 0; nb < 8; ++nb) {
    #pragma unroll
    for (int r = 0; r < 4; ++r) {
      r0.ab[(w * 16 + lg * 4 + r) * 136 + nb * 16 + lr] = f2bf(Aacc[nb][r]);
    }
  }
  // stage V^T (from prefetched regs)
  #pragma unroll
  for (int u = 0; u < 4; ++u) {
    float4 a = (u == 0) ? fva : (u == 1) ? fvb : (u == 2) ? fvc : fvd;
    int id = t + u * 512;
    int pos = id >> 4, e = (id & 15) * 4;
    r1.vt[(e + 0) * 136 + pos] = f2bf(a.x);
    r1.vt[(e + 1) * 136 + pos] = f2bf(a.y);
    r1.vt[(e + 2) * 136 + pos] = f2bf(a.z);
    r1.vt[(e + 3) * 136 + pos] = f2bf(a.w);
  }
  __syncthreads();  // B3

  // O2^T: O^T += V^T A^T ; divide ; store
  __builtin_amdgcn_s_setprio(1);
  #pragma unroll
  for (int ks = 0; ks < 4; ++ks) {
    short8 av = *(const short8*)&r1.vt[(eb * 16 + lr) * 136 + ks * 32 + lg * 8];
    #pragma unroll
    for (int nq = 0; nq < 4; ++nq) {
      int jb = qh * 4 + nq;
      if (ks <= (jb >> 1)) {
        short8 ba = *(const short8*)&r0.ab[(jb * 16 + lr) * 136 + ks * 32 + lg * 8];
        Oacc[nq] = MFMA(av, ba, Oacc[nq], 0, 0, 0);
      }
    }
  }
  __builtin_amdgcn_s_setprio(0);
  #pragma unroll
  for (int nq = 0; nq < 4; ++nq) {
    const int qrow = (qh * 4 + nq) * 16 + lr;
    float dinv = __builtin_amdgcn_rcpf(den[qrow]);
    float4 o = make_float4(Oacc[nq][0] * dinv, Oacc[nq][1] * dinv,
                           Oacc[nq][2] * dinv, Oacc[nq][3] * dinv);
    *(float4*)(outg + (size_t)qrow * 64 + eb * 16 + lg * 4) = o;
  }
}

extern "C" void kernel_launch(void* const* d_in, const int* in_sizes, int n_in,
                              void* d_out, int out_size, void* d_ws, size_t ws_size,
                              hipStream_t stream) {
  const float* q = (const float*)d_in[0];
  const float* k = (const float*)d_in[1];
  const float* v = (const float*)d_in[2];
  const float* proj = (const float*)d_in[3];
  float* out = (float*)d_out;
  ushort* prjg = (ushort*)d_ws;
  float* ksumg = (float*)((char*)d_ws + 32768);
  ushort* stg = (ushort*)((char*)d_ws + 32768 + 524288);  // ~17.3 MB total

  k0_proj<<<16, 256, 0, stream>>>(proj, prjg);
  k1_chunksums<<<512, 512, 0, stream>>>(k, v, prjg, ksumg, stg);
  k2_scan<<<16 * 33, 256, 0, stream>>>(ksumg, stg);
  k3_out<<<512, 512, 0, stream>>>(q, k, v, prjg, ksumg, stg, out);
}

// Round 14
// 66.641 us; speedup vs baseline: 1.0395x; 1.0395x over previous
//
#include <hip/hip_runtime.h>
#include <hip/hip_bf16.h>

#define NORM 0.35355339059327373f  // 64^-0.25
#define EPS 1e-6f

typedef __attribute__((ext_vector_type(8))) short short8;
typedef __attribute__((ext_vector_type(4))) float floatx4;

static __device__ __forceinline__ ushort f2bf(float x) {
  union { __hip_bfloat16 h; ushort u; } c;
  c.h = __float2bfloat16(x);
  return c.u;
}
static __device__ __forceinline__ ushort2 f2bf2(float a, float b) {
  union { __hip_bfloat162 h; ushort2 u; } c;
  c.h = __float22bfloat162_rn(make_float2(a, b));
  return c.u;
}
static __device__ __forceinline__ float sigm(float s) {
  return __builtin_amdgcn_rcpf(1.f + __expf(-s)) + EPS;
}
#define MFMA __builtin_amdgcn_mfma_f32_16x16x32_bf16

// ws layout (bytes):
//   [0, 32768)            prjg: bf16(proj*NORM) [256 feat][64 d]
//   [32768, 557056)       ksumg: f32 per-chunk Ksum [512][256] (k2 -> exclusive prefix)
//   [557056, +16777216)   stg: bf16 St [512][64 e][256 f] (k2 -> exclusive prefix)

// ---------------- K0: pre-convert proj ----------------
__global__ __launch_bounds__(256) void k0_proj(const float* __restrict__ proj,
                                               ushort* __restrict__ prjg) {
  int id = blockIdx.x * 256 + threadIdx.x;  // 4096 float4s
  float4 a = ((const float4*)proj)[id];
  ushort2 lo = f2bf2(a.x * NORM, a.y * NORM);
  ushort2 hi = f2bf2(a.z * NORM, a.w * NORM);
  ((ushort4*)prjg)[id] = make_ushort4(lo.x, lo.y, hi.x, hi.y);
}

// ---------------- K1: per-chunk sums (8 waves, f-quarters, kpt dbuf, pj prefetch) ----------------
__global__ __launch_bounds__(512, 4) void k1_chunksums(
    const float* __restrict__ k, const float* __restrict__ v,
    const ushort* __restrict__ prjg, float* __restrict__ ksumg,
    ushort* __restrict__ stg) {
  __shared__ __align__(16) ushort xk[128 * 72];       // k chunk pos-major bf16
  __shared__ __align__(16) ushort vt[80 * 136];       // V e-major + ones row e=64
  __shared__ __align__(16) ushort kpt[2 * 64 * 136];  // Kp quarter, feat-major, dbuf
  const int t = threadIdx.x;
  const int w = t >> 6, l = t & 63, lr = l & 15, lg = l >> 4;
  const int blk = blockIdx.x;
  const float4* kg4 = (const float4*)(k + (size_t)blk * 8192);
  const float4* vg4 = (const float4*)(v + (size_t)blk * 8192);

  // issue quarter-0 prjg fragments first (latency hides under staging)
  short8 pj[2][8];
  #pragma unroll
  for (int i = 0; i < 4; ++i) {
    pj[0][2 * i] = *(const short8*)&prjg[(size_t)(i * 16 + lr) * 64 + lg * 8];
    pj[0][2 * i + 1] = *(const short8*)&prjg[(size_t)(i * 16 + lr) * 64 + 32 + lg * 8];
  }

  #pragma unroll
  for (int u = 0; u < 4; ++u) {
    int id = t + u * 512;
    float4 a = kg4[id];
    int row = id >> 4, c = (id & 15) * 4;
    ushort2 p0 = f2bf2(a.x, a.y), p1 = f2bf2(a.z, a.w);
    *(ushort4*)&xk[row * 72 + c] = make_ushort4(p0.x, p0.y, p1.x, p1.y);
  }
  #pragma unroll
  for (int u = 0; u < 4; ++u) {
    int id = t + u * 512;
    float4 a = vg4[id];
    int pos = id >> 4, e = (id & 15) * 4;
    vt[(e + 0) * 136 + pos] = f2bf(a.x);
    vt[(e + 1) * 136 + pos] = f2bf(a.y);
    vt[(e + 2) * 136 + pos] = f2bf(a.z);
    vt[(e + 3) * 136 + pos] = f2bf(a.w);
  }
  #pragma unroll
  for (int u = 0; u < 4; ++u) {  // rows 64..79: ones row then zeros
    int id = t + u * 512;
    int rr = id >> 7, pos = id & 127;
    vt[(64 + rr) * 136 + pos] = (rr == 0) ? (ushort)0x3F80 : (ushort)0;
  }
  __syncthreads();

  const int fb = w & 3, g = w >> 2;
  float* kb = ksumg + (size_t)blk * 256;
  ushort* stbp = stg + (size_t)blk * 16384;

  // loop-invariant xk fragments (wave's pos-block rows)
  const short8 a0 = *(const short8*)&xk[(w * 16 + lr) * 72 + lg * 8];
  const short8 a1 = *(const short8*)&xk[(w * 16 + lr) * 72 + 32 + lg * 8];

  #pragma unroll
  for (int qd = 0; qd < 4; ++qd) {
    const int cur = qd & 1, nxt = cur ^ 1;
    ushort* kq = kpt + cur * 8704;
    // features: wave w = pos-block w; M=pos, N=feat(4 blocks), K=d(64)
    #pragma unroll
    for (int fb2 = 0; fb2 < 4; ++fb2) {
      floatx4 fa = (floatx4){0.f, 0.f, 0.f, 0.f};
      fa = MFMA(a0, pj[cur][2 * fb2], fa, 0, 0, 0);
      fa = MFMA(a1, pj[cur][2 * fb2 + 1], fa, 0, 0, 0);
      // C: col=feat(lr), row=pos(w*16+lg*4+r) -> 4 consecutive pos, b64
      ushort2 p0 = f2bf2(sigm(fa[0]), sigm(fa[1]));
      ushort2 p1 = f2bf2(sigm(fa[2]), sigm(fa[3]));
      *(ushort4*)&kq[(fb2 * 16 + lr) * 136 + w * 16 + lg * 4] =
          make_ushort4(p0.x, p0.y, p1.x, p1.y);
    }
    __syncthreads();  // kq[cur] ready (single barrier per stage; dbuf makes it safe)

    if (qd < 3) {  // prefetch next quarter's prjg fragments (hide under S-GEMM)
      #pragma unroll
      for (int i = 0; i < 4; ++i) {
        pj[nxt][2 * i] =
            *(const short8*)&prjg[(size_t)((qd + 1) * 64 + i * 16 + lr) * 64 + lg * 8];
        pj[nxt][2 * i + 1] =
            *(const short8*)&prjg[(size_t)((qd + 1) * 64 + i * 16 + lr) * 64 + 32 + lg * 8];
      }
    }

    // S-GEMM quarter: M=feat(fb), N=e'(g, 2+g, (+ones if g==0)), K=pos(128)
    {
      floatx4 s0 = (floatx4){0.f, 0.f, 0.f, 0.f};
      floatx4 s1 = (floatx4){0.f, 0.f, 0.f, 0.f};
      floatx4 s2 = (floatx4){0.f, 0.f, 0.f, 0.f};
      __builtin_amdgcn_s_setprio(1);
      #pragma unroll
      for (int ks = 0; ks < 4; ++ks) {
        short8 a = *(const short8*)&kq[(fb * 16 + lr) * 136 + ks * 32 + lg * 8];
        short8 bA = *(const short8*)&vt[(g * 16 + lr) * 136 + ks * 32 + lg * 8];
        s0 = MFMA(a, bA, s0, 0, 0, 0);
        short8 bB = *(const short8*)&vt[((2 + g) * 16 + lr) * 136 + ks * 32 + lg * 8];
        s1 = MFMA(a, bB, s1, 0, 0, 0);
        if (g == 0) {
          short8 bC = *(const short8*)&vt[(64 + lr) * 136 + ks * 32 + lg * 8];
          s2 = MFMA(a, bC, s2, 0, 0, 0);
        }
      }
      __builtin_amdgcn_s_setprio(0);
      {
        ushort2 q0 = f2bf2(s0[0], s0[1]), q1 = f2bf2(s0[2], s0[3]);
        *(ushort4*)&stbp[(size_t)(g * 16 + lr) * 256 + qd * 64 + fb * 16 + lg * 4] =
            make_ushort4(q0.x, q0.y, q1.x, q1.y);
        ushort2 r0_ = f2bf2(s1[0], s1[1]), r1_ = f2bf2(s1[2], s1[3]);
        *(ushort4*)&stbp[(size_t)((2 + g) * 16 + lr) * 256 + qd * 64 + fb * 16 + lg * 4] =
            make_ushort4(r0_.x, r0_.y, r1_.x, r1_.y);
      }
      if (g == 0 && lr == 0) {
        #pragma unroll
        for (int r = 0; r < 4; ++r) kb[qd * 64 + fb * 16 + lg * 4 + r] = s2[r];
      }
    }
    // no trailing barrier: next qd writes the other kpt buffer
  }
}

// ---------------- K2: exclusive scan over 32 chunks per head ----------------
// batch-load all 32 chunk values (independent loads in flight), then scan in regs
__global__ __launch_bounds__(256) void k2_scan(float* __restrict__ ksumg,
                                               ushort* __restrict__ stg) {
  int bh = blockIdx.x / 33, part = blockIdx.x % 33, t = threadIdx.x;
  if (part < 32) {
    uint* p = (uint*)stg + (size_t)bh * 32 * 8192 + part * 256 + t;
    uint tmp[32];
    #pragma unroll
    for (int c = 0; c < 32; ++c) tmp[c] = p[(size_t)c * 8192];
    float r0 = 0.f, r1 = 0.f;
    #pragma unroll
    for (int c = 0; c < 32; ++c) {
      float a = __uint_as_float(tmp[c] << 16);
      float b = __uint_as_float(tmp[c] & 0xffff0000u);
      ushort2 w2 = f2bf2(r0, r1);
      p[(size_t)c * 8192] = (uint)w2.x | ((uint)w2.y << 16);
      r0 += a; r1 += b;
    }
  } else {
    float* p = ksumg + (size_t)bh * 32 * 256 + t;
    float tmp[32];
    #pragma unroll
    for (int c = 0; c < 32; ++c) tmp[c] = p[(size_t)c * 256];
    float run = 0.f;
    #pragma unroll
    for (int c = 0; c < 32; ++c) {
      p[(size_t)c * 256] = run;
      run += tmp[c];
    }
  }
}

// ---------------- K3: per-chunk output (8 waves, f-quarters, 2 blk/CU, pipelined) ----------------
__global__ __launch_bounds__(512, 4) void k3_out(
    const float* __restrict__ q, const float* __restrict__ k,
    const float* __restrict__ v, const ushort* __restrict__ prjg,
    const float* __restrict__ ksumg, const ushort* __restrict__ stg,
    float* __restrict__ out) {
  __shared__ __align__(16) union U0 {
    struct { ushort xq[128 * 72]; ushort xk[128 * 72]; } s;  // 36864 B
    ushort ab[128 * 136];                                    // 34816 B (tail)
  } r0;
  __shared__ __align__(16) union U1 {
    ushort qp[128 * 72];   // Qp quarter, pos-major
    ushort vt[64 * 136];   // V^T (tail)
  } r1;
  __shared__ __align__(16) ushort kp[144 * 72];  // Kp quarter + Kprev row 128 (+zeros)
  __shared__ float den[128];
  // LDS total = 36864 + 18432 + 20736 + 512 = 76544 B -> 2 blocks/CU

  const int t = threadIdx.x;
  const int w = t >> 6, l = t & 63, lr = l & 15, lg = l >> 4;
  const int blk = blockIdx.x;
  const float4* qg4 = (const float4*)(q + (size_t)blk * 8192);
  const float4* kg4 = (const float4*)(k + (size_t)blk * 8192);
  const float4* vg4 = (const float4*)(v + (size_t)blk * 8192);
  const float* ksb = ksumg + (size_t)blk * 256;
  const ushort* stb = stg + (size_t)blk * 16384;
  float* outg = out + (size_t)blk * 8192;

  // Kprev scalars (wave-0 lanes hold them; written into kp row 128 per quarter)
  float kv0 = 0.f, kv1 = 0.f, kv2 = 0.f, kv3 = 0.f;
  if (t < 64) {
    kv0 = ksb[t]; kv1 = ksb[64 + t]; kv2 = ksb[128 + t]; kv3 = ksb[192 + t];
  }
  // zero kp rows 129..143 once (dqr B-fragment padding)
  for (int id = t; id < 1080; id += 512) kp[9288 + id] = (ushort)0;

  // stage xq/xk
  #pragma unroll
  for (int u = 0; u < 4; ++u) {
    int id = t + u * 512;
    float4 a = qg4[id];
    float4 c = kg4[id];
    int row = id >> 4, cc = (id & 15) * 4;
    ushort2 a0 = f2bf2(a.x, a.y), a1 = f2bf2(a.z, a.w);
    *(ushort4*)&r0.s.xq[row * 72 + cc] = make_ushort4(a0.x, a0.y, a1.x, a1.y);
    ushort2 c0 = f2bf2(c.x, c.y), c1 = f2bf2(c.z, c.w);
    *(ushort4*)&r0.s.xk[row * 72 + cc] = make_ushort4(c0.x, c0.y, c1.x, c1.y);
  }
  __syncthreads();  // B0

  floatx4 Aacc[9];  // A blocks 0..7 (pos-block w) + dqr column (8)
  floatx4 Oacc[4];  // O tiles (eb, qh)
  #pragma unroll
  for (int i = 0; i < 9; ++i) Aacc[i] = (floatx4){0.f, 0.f, 0.f, 0.f};
  #pragma unroll
  for (int i = 0; i < 4; ++i) Oacc[i] = (floatx4){0.f, 0.f, 0.f, 0.f};
  const int px = w & 1, fbw = w >> 1;  // feature role
  const int eb = w & 3, qh = w >> 2;   // O role
  float4 fva, fvb, fvc, fvd;

  // 2-deep fragment pipeline: pjc/stc[cur] consumed this quarter, [nxt] loaded
  // after B1 so the latency hides under A/O1.  Indices static after full unroll.
  short8 pjc[2][2], stc[2][2];
  pjc[0][0] = *(const short8*)&prjg[(size_t)(fbw * 16 + lr) * 64 + lg * 8];
  pjc[0][1] = *(const short8*)&prjg[(size_t)(fbw * 16 + lr) * 64 + 32 + lg * 8];
  stc[0][0] = *(const short8*)&stb[(size_t)(eb * 16 + lr) * 256 + lg * 8];
  stc[0][1] = *(const short8*)&stb[(size_t)(eb * 16 + lr) * 256 + 32 + lg * 8];

  #pragma unroll
  for (int qd = 0; qd < 4; ++qd) {
    const int cur = qd & 1, nxt = cur ^ 1;
    if (t < 64) {
      float kvq = qd == 0 ? kv0 : qd == 1 ? kv1 : qd == 2 ? kv2 : kv3;
      kp[9216 + t] = f2bf(kvq + EPS);  // row 128
    }
    // features: M=feat(fbw), N=pos(8 blocks in 2 halves), K=d(64)
    const ushort* xb = px ? r0.s.xk : r0.s.xq;
    ushort* xp = px ? kp : r1.qp;
    #pragma unroll
    for (int h = 0; h < 2; ++h) {
      floatx4 fa[4];
      #pragma unroll
      for (int i = 0; i < 4; ++i) fa[i] = (floatx4){0.f, 0.f, 0.f, 0.f};
      #pragma unroll
      for (int ks2 = 0; ks2 < 2; ++ks2) {
        short8 a = pjc[cur][ks2];
        #pragma unroll
        for (int nb4 = 0; nb4 < 4; ++nb4) {
          int nb = h * 4 + nb4;
          short8 b = *(const short8*)&xb[(nb * 16 + lr) * 72 + ks2 * 32 + lg * 8];
          fa[nb4] = MFMA(a, b, fa[nb4], 0, 0, 0);
        }
      }
      #pragma unroll
      for (int nb4 = 0; nb4 < 4; ++nb4) {
        int nb = h * 4 + nb4;
        // C: col=pos(lr), row=feat (4 consecutive) -> b64 into [pos][feat]
        ushort2 p0 = f2bf2(sigm(fa[nb4][0]), sigm(fa[nb4][1]));
        ushort2 p1 = f2bf2(sigm(fa[nb4][2]), sigm(fa[nb4][3]));
        *(ushort4*)&xp[(nb * 16 + lr) * 72 + fbw * 16 + lg * 4] =
            make_ushort4(p0.x, p0.y, p1.x, p1.y);
      }
    }
    __syncthreads();  // B1(qd)

    if (qd < 3) {  // prefetch next quarter's fragments (lands during A/O1)
      pjc[nxt][0] = *(const short8*)&prjg[(size_t)((qd + 1) * 64 + fbw * 16 + lr) * 64 + lg * 8];
      pjc[nxt][1] = *(const short8*)&prjg[(size_t)((qd + 1) * 64 + fbw * 16 + lr) * 64 + 32 + lg * 8];
      stc[nxt][0] = *(const short8*)&stb[(size_t)(eb * 16 + lr) * 256 + (qd + 1) * 64 + lg * 8];
      stc[nxt][1] = *(const short8*)&stb[(size_t)(eb * 16 + lr) * 256 + (qd + 1) * 64 + 32 + lg * 8];
    }
    if (qd == 3) {  // tail V loads: latency hides under last A/O1 + B2
      fva = vg4[t]; fvb = vg4[t + 512]; fvc = vg4[t + 1024]; fvd = vg4[t + 1536];
    }

    __builtin_amdgcn_s_setprio(1);
    // A-GEMM (causal, static unroll+predicate: rule #20) + dqr column
    #pragma unroll
    for (int ks = 0; ks < 2; ++ks) {
      short8 aq = *(const short8*)&r1.qp[(w * 16 + lr) * 72 + ks * 32 + lg * 8];
      #pragma unroll
      for (int nb = 0; nb < 8; ++nb) {
        if (nb <= w) {
          short8 bk = *(const short8*)&kp[(nb * 16 + lr) * 72 + ks * 32 + lg * 8];
          Aacc[nb] = MFMA(aq, bk, Aacc[nb], 0, 0, 0);
        }
      }
      short8 bx = *(const short8*)&kp[(128 + lr) * 72 + ks * 32 + lg * 8];
      Aacc[8] = MFMA(aq, bx, Aacc[8], 0, 0, 0);
    }
    // O1^T: O^T += S_prev^T Qp^T (A-frag from regs)
    #pragma unroll
    for (int ks = 0; ks < 2; ++ks) {
      short8 as = stc[cur][ks];
      #pragma unroll
      for (int nq = 0; nq < 4; ++nq) {
        int jb = qh * 4 + nq;
        short8 bq = *(const short8*)&r1.qp[(jb * 16 + lr) * 72 + ks * 32 + lg * 8];
        Oacc[nq] = MFMA(as, bq, Oacc[nq], 0, 0, 0);
      }
    }
    __builtin_amdgcn_s_setprio(0);
    __syncthreads();  // B2(qd)
  }

  // mask + rowsum -> den
  #pragma unroll
  for (int r = 0; r < 4; ++r) {
    const int qrow = w * 16 + lg * 4 + r;
    float s = 0.f;
    #pragma unroll
    for (int nb = 0; nb < 8; ++nb) {
      float val = Aacc[nb][r];
      if (nb * 16 + lr > qrow) val = 0.f;
      Aacc[nb][r] = val;
      s += val;
    }
    s += __shfl_xor(s, 1); s += __shfl_xor(s, 2);
    s += __shfl_xor(s, 4); s += __shfl_xor(s, 8);
    if (lr == 0) den[qrow] = s + Aacc[8][r];
  }
  // scatter masked A -> ab
  #pragma unroll
  for (int nb = 0; nb < 8; ++nb) {
    #pragma unroll
    for (int r = 0; r < 4; ++r) {
      r0.ab[(w * 16 + lg * 4 + r) * 136 + nb * 16 + lr] = f2bf(Aacc[nb][r]);
    }
  }
  // stage V^T (from prefetched regs)
  #pragma unroll
  for (int u = 0; u < 4; ++u) {
    float4 a = (u == 0) ? fva : (u == 1) ? fvb : (u == 2) ? fvc : fvd;
    int id = t + u * 512;
    int pos = id >> 4, e = (id & 15) * 4;
    r1.vt[(e + 0) * 136 + pos] = f2bf(a.x);
    r1.vt[(e + 1) * 136 + pos] = f2bf(a.y);
    r1.vt[(e + 2) * 136 + pos] = f2bf(a.z);
    r1.vt[(e + 3) * 136 + pos] = f2bf(a.w);
  }
  __syncthreads();  // B3

  // O2^T: O^T += V^T A^T ; divide ; store
  __builtin_amdgcn_s_setprio(1);
  #pragma unroll
  for (int ks = 0; ks < 4; ++ks) {
    short8 av = *(const short8*)&r1.vt[(eb * 16 + lr) * 136 + ks * 32 + lg * 8];
    #pragma unroll
    for (int nq = 0; nq < 4; ++nq) {
      int jb = qh * 4 + nq;
      if (ks <= (jb >> 1)) {
        short8 ba = *(const short8*)&r0.ab[(jb * 16 + lr) * 136 + ks * 32 + lg * 8];
        Oacc[nq] = MFMA(av, ba, Oacc[nq], 0, 0, 0);
      }
    }
  }
  __builtin_amdgcn_s_setprio(0);
  #pragma unroll
  for (int nq = 0; nq < 4; ++nq) {
    const int qrow = (qh * 4 + nq) * 16 + lr;
    float dinv = __builtin_amdgcn_rcpf(den[qrow]);
    float4 o = make_float4(Oacc[nq][0] * dinv, Oacc[nq][1] * dinv,
                           Oacc[nq][2] * dinv, Oacc[nq][3] * dinv);
    *(float4*)(outg + (size_t)qrow * 64 + eb * 16 + lg * 4) = o;
  }
}

extern "C" void kernel_launch(void* const* d_in, const int* in_sizes, int n_in,
                              void* d_out, int out_size, void* d_ws, size_t ws_size,
                              hipStream_t stream) {
  const float* q = (const float*)d_in[0];
  const float* k = (const float*)d_in[1];
  const float* v = (const float*)d_in[2];
  const float* proj = (const float*)d_in[3];
  float* out = (float*)d_out;
  ushort* prjg = (ushort*)d_ws;
  float* ksumg = (float*)((char*)d_ws + 32768);
  ushort* stg = (ushort*)((char*)d_ws + 32768 + 524288);  // ~17.3 MB total

  k0_proj<<<16, 256, 0, stream>>>(proj, prjg);
  k1_chunksums<<<512, 512, 0, stream>>>(k, v, prjg, ksumg, stg);
  k2_scan<<<16 * 33, 256, 0, stream>>>(ksumg, stg);
  k3_out<<<512, 512, 0, stream>>>(q, k, v, prjg, ksumg, stg, out);
}